// Round 2
// baseline (673.663 us; speedup 1.0000x reference)
//
#include <hip/hip_runtime.h>

#define BLOCK 256
#define RPB   512                          /* rows per block; labels LDS = 2 KB */
#define C     128
#define F4_PER_ROW   (C / 4)               /* 32 */
#define F4_PER_BLOCK (RPB * F4_PER_ROW)    /* 16384 */
#define ITERS        (F4_PER_BLOCK / BLOCK)/* 64 */

__global__ __launch_bounds__(BLOCK) void MultiCrossEntropyLoss_kernel(
    const float4* __restrict__ predicts4,
    const int*    __restrict__ labels,
    float*        __restrict__ out,
    int n, float inv_n)
{
    __shared__ int   lds_lab[RPB];
    __shared__ float wave_sums[BLOCK / 64];

    const int row0 = blockIdx.x * RPB;
    const int rows = min(RPB, n - row0);

    // Preload this block's labels once (coalesced); hot loop then has NO
    // global dependency other than the pure predicts stream.
    for (int r = threadIdx.x; r < rows; r += BLOCK)
        lds_lab[r] = labels[row0 + r];
    __syncthreads();

    const int slot  = threadIdx.x & 31;    // which float4 of its row this thread owns (loop-invariant)
    const int rbase = threadIdx.x >> 5;    // row-in-chunk base (0..7)
    const float4* p = predicts4 + (size_t)row0 * F4_PER_ROW + threadIdx.x;

    float s0 = 0.0f, s1 = 0.0f;

    if (rows == RPB) {
        // Branch-free body: loads are unconditional and label-independent, so
        // unroll-8 clusters 8 global_load_dwordx4 back-to-back (8 KB/wave in
        // flight). Selection + log are if-converted (cndmask), no cbranch.
        #pragma unroll 8
        for (int k = 0; k < ITERS; ++k) {
            const float4 v   = p[k * BLOCK];
            const int    lab = lds_lab[rbase + (k << 3)];  // LDS broadcast per half-wave
            const float x01 = (lab & 1) ? v.y : v.x;
            const float x23 = (lab & 1) ? v.w : v.z;
            const float x   = (lab & 2) ? x23 : x01;
            const float lg  = __logf(x);                   // speculated on all lanes; x>0 always
            const float c   = ((lab >> 2) == slot) ? lg : 0.0f;
            if (k & 1) s1 += c; else s0 += c;              // two accumulators break the add chain
        }
    } else {
        // Tail block (n not a multiple of RPB): guarded scalar-ish path.
        for (int k = 0; k < ITERS; ++k) {
            const int idx = threadIdx.x + k * BLOCK;
            const int r   = idx >> 5;
            if (r < rows) {
                const float4 v   = p[k * BLOCK];
                const int    lab = lds_lab[r];
                const float x01 = (lab & 1) ? v.y : v.x;
                const float x23 = (lab & 1) ? v.w : v.z;
                const float x   = (lab & 2) ? x23 : x01;
                if ((lab >> 2) == slot) s0 += __logf(x);
            }
        }
    }

    float s = s0 + s1;

    // Wave (64-lane) shuffle reduction.
    #pragma unroll
    for (int off = 32; off > 0; off >>= 1)
        s += __shfl_down(s, off, 64);

    const int lane = threadIdx.x & 63;
    const int wv   = threadIdx.x >> 6;
    if (lane == 0) wave_sums[wv] = s;
    __syncthreads();

    if (threadIdx.x == 0) {
        float bs = wave_sums[0] + wave_sums[1] + wave_sums[2] + wave_sums[3];
        // loss = -(1/N) * sum(log p); one atomic per block, pre-scaled.
        atomicAdd(out, -bs * inv_n);
    }
}

extern "C" void kernel_launch(void* const* d_in, const int* in_sizes, int n_in,
                              void* d_out, int out_size, void* d_ws, size_t ws_size,
                              hipStream_t stream) {
    const float* predicts = (const float*)d_in[0];
    const int*   labels   = (const int*)d_in[1];
    float*       out      = (float*)d_out;
    const int n = in_sizes[1];  // N = number of rows/labels

    // d_out is re-poisoned before every timed replay; we accumulate with
    // atomics, so zero it first (hipMemsetAsync is graph-capture-safe).
    hipMemsetAsync(d_out, 0, sizeof(float), stream);

    const int grid = (n + RPB - 1) / RPB;   // 2048 blocks for N=1M
    MultiCrossEntropyLoss_kernel<<<grid, BLOCK, 0, stream>>>(
        (const float4*)predicts, labels, out, n, 1.0f / (float)n);
}

// Round 3
// 604.910 us; speedup vs baseline: 1.1137x; 1.1137x over previous
//
#include <hip/hip_runtime.h>

#define BLOCK 256
#define PER_THREAD 2   /* grid = N/(256*2) = 2048 blocks = 8 blocks/CU = 32 waves/CU (full occupancy) */
#define C 128

__global__ __launch_bounds__(BLOCK) void MultiCrossEntropyLoss_kernel(
    const float* __restrict__ predicts,
    const int*   __restrict__ labels,
    float* __restrict__ out,
    int n, float inv_n)
{
    const int tid = blockIdx.x * BLOCK + threadIdx.x;
    const int i0  = tid * PER_THREAD;

    float s = 0.0f;
    if (i0 + PER_THREAD - 1 < n) {
        // One 8B coalesced label load, then 2 independent gathers (MLP=2/thread,
        // 32 waves/CU of contexts to overlap the label->gather latency chain).
        int2 lab = *reinterpret_cast<const int2*>(labels + i0);
        float p0 = predicts[(i0 + 0) * C + lab.x];
        float p1 = predicts[(i0 + 1) * C + lab.y];
        s = __logf(p0) + __logf(p1);
    } else {
        for (int i = i0; i < n; ++i)
            s += __logf(predicts[i * C + labels[i]]);
    }

    // Wave (64-lane) shuffle reduction.
    #pragma unroll
    for (int off = 32; off > 0; off >>= 1)
        s += __shfl_down(s, off, 64);

    // Cross-wave reduction via LDS (BLOCK/64 = 4 waves).
    __shared__ float wave_sums[BLOCK / 64];
    const int lane = threadIdx.x & 63;
    const int wv   = threadIdx.x >> 6;
    if (lane == 0) wave_sums[wv] = s;
    __syncthreads();

    if (threadIdx.x == 0) {
        float bs = wave_sums[0] + wave_sums[1] + wave_sums[2] + wave_sums[3];
        // loss = -(1/N) * sum(log p); one atomic per block, pre-scaled.
        atomicAdd(out, -bs * inv_n);
    }
}

extern "C" void kernel_launch(void* const* d_in, const int* in_sizes, int n_in,
                              void* d_out, int out_size, void* d_ws, size_t ws_size,
                              hipStream_t stream) {
    const float* predicts = (const float*)d_in[0];
    const int*   labels   = (const int*)d_in[1];
    float*       out      = (float*)d_out;
    const int n = in_sizes[1];  // N = number of rows/labels

    // d_out is re-poisoned before every timed replay; we accumulate with
    // atomics, so zero it first (hipMemsetAsync is graph-capture-safe).
    hipMemsetAsync(d_out, 0, sizeof(float), stream);

    const int per_block = BLOCK * PER_THREAD;
    const int grid = (n + per_block - 1) / per_block;
    MultiCrossEntropyLoss_kernel<<<grid, BLOCK, 0, stream>>>(
        predicts, labels, out, n, 1.0f / (float)n);
}

// Round 4
// 590.399 us; speedup vs baseline: 1.1410x; 1.0246x over previous
//
#include <hip/hip_runtime.h>

#define BLOCK 256
#define PER_THREAD 4   /* grid = N/1024 = 1024 blocks; R0 geometry (best measured) */
#define C 128

__global__ __launch_bounds__(BLOCK) void MultiCrossEntropyLoss_kernel(
    const float* __restrict__ predicts,
    const int*   __restrict__ labels,
    float* __restrict__ out,
    int n, float inv_n)
{
    const int tid = blockIdx.x * BLOCK + threadIdx.x;
    const int i0  = tid * PER_THREAD;

    float s = 0.0f;
    if (i0 + PER_THREAD - 1 < n) {
        // Vector label load (coalesced), then 4 independent gathers.
        // Gathers are nontemporal (nt): zero reuse by construction, so
        // evict-first / no-allocate avoids 128B L2-line overfetch for a 4B
        // payload and stops thrashing L2/L3 with never-re-read lines.
        int4 lab = *reinterpret_cast<const int4*>(labels + i0);
        float p0 = __builtin_nontemporal_load(predicts + (size_t)(i0 + 0) * C + lab.x);
        float p1 = __builtin_nontemporal_load(predicts + (size_t)(i0 + 1) * C + lab.y);
        float p2 = __builtin_nontemporal_load(predicts + (size_t)(i0 + 2) * C + lab.z);
        float p3 = __builtin_nontemporal_load(predicts + (size_t)(i0 + 3) * C + lab.w);
        s = __logf(p0) + __logf(p1) + __logf(p2) + __logf(p3);
    } else {
        for (int i = i0; i < n; ++i)
            s += __logf(predicts[(size_t)i * C + labels[i]]);
    }

    // Wave (64-lane) shuffle reduction.
    #pragma unroll
    for (int off = 32; off > 0; off >>= 1)
        s += __shfl_down(s, off, 64);

    // Cross-wave reduction via LDS (BLOCK/64 = 4 waves).
    __shared__ float wave_sums[BLOCK / 64];
    const int lane = threadIdx.x & 63;
    const int wv   = threadIdx.x >> 6;
    if (lane == 0) wave_sums[wv] = s;
    __syncthreads();

    if (threadIdx.x == 0) {
        float bs = wave_sums[0] + wave_sums[1] + wave_sums[2] + wave_sums[3];
        // loss = -(1/N) * sum(log p); one atomic per block, pre-scaled.
        atomicAdd(out, -bs * inv_n);
    }
}

extern "C" void kernel_launch(void* const* d_in, const int* in_sizes, int n_in,
                              void* d_out, int out_size, void* d_ws, size_t ws_size,
                              hipStream_t stream) {
    const float* predicts = (const float*)d_in[0];
    const int*   labels   = (const int*)d_in[1];
    float*       out      = (float*)d_out;
    const int n = in_sizes[1];  // N = number of rows/labels

    // d_out is re-poisoned before every timed replay; we accumulate with
    // atomics, so zero it first (hipMemsetAsync is graph-capture-safe).
    hipMemsetAsync(d_out, 0, sizeof(float), stream);

    const int per_block = BLOCK * PER_THREAD;
    const int grid = (n + per_block - 1) / per_block;
    MultiCrossEntropyLoss_kernel<<<grid, BLOCK, 0, stream>>>(
        predicts, labels, out, n, 1.0f / (float)n);
}